// Round 2
// baseline (309.242 us; speedup 1.0000x reference)
//
#include <hip/hip_runtime.h>
#include <hip/hip_bf16.h>

#define NN 25000     // nodes
#define NE 100000    // edges
#define FIN 32
#define FE 8
#define EMB 32
#define NG 512
#define PCOLS 576    // 16*32 (w2 rows) + 32 (b2 row) + 32 (root row)

// P[n, c] = sum_i x[n,i] * W2T[i,c]
//   c in [0,512):   W2T[i,c] = w2[(c>>5)*1024 + i*32 + (c&31)]
//   c in [512,544): b2[i*32 + (c-512)]
//   c in [544,576): root[i*32 + (c-544)]
__global__ __launch_bounds__(256) void pgemm_kernel(
        const float* __restrict__ xf,
        const float* __restrict__ w2, const float* __restrict__ b2v,
        const float* __restrict__ root, float* __restrict__ P) {
    __shared__ float xs[16][FIN];
    int tid = threadIdx.x;
    int n0 = blockIdx.x * 16;
    for (int idx = tid; idx < 16 * FIN; idx += 256) {
        int nn = idx >> 5, i = idx & 31;
        int n = n0 + nn;
        xs[nn][i] = (n < NN) ? xf[n * FIN + i] : 0.f;
    }
    __syncthreads();
    int cx = tid & 63, ny = tid >> 6;   // 64 col-lanes x 4 node rows
    for (int chunk = 0; chunk < 9; ++chunk) {
        int c = chunk * 64 + cx;
        const float* wp;                 // all sources have i-stride 32
        if (c < 512)      { int k = c >> 5, o = c & 31; wp = w2 + k * 1024 + o; }
        else if (c < 544) { wp = b2v + (c - 512); }
        else              { wp = root + (c - 544); }
        float a0 = 0.f, a1 = 0.f, a2 = 0.f, a3 = 0.f;
        for (int i = 0; i < 32; ++i) {
            float w = wp[i * 32];
            a0 += xs[ny     ][i] * w;
            a1 += xs[ny +  4][i] * w;
            a2 += xs[ny +  8][i] * w;
            a3 += xs[ny + 12][i] * w;
        }
        int n;
        n = n0 + ny;      if (n < NN) P[(size_t)n * PCOLS + c] = a0;
        n = n0 + ny + 4;  if (n < NN) P[(size_t)n * PCOLS + c] = a1;
        n = n0 + ny + 8;  if (n < NN) P[(size_t)n * PCOLS + c] = a2;
        n = n0 + ny + 12; if (n < NN) P[(size_t)n * PCOLS + c] = a3;
    }
}

// per edge: h = relu(ea@w1+b1); msg[o] = sum_k h[k]*P[src,k*32+o] + P[src,512+o];
// atomicAdd into agg[dst,o]. 32 lanes per edge, 8 edges per 256-thread block.
__global__ __launch_bounds__(256) void edge_msg_kernel(
        const float* __restrict__ ea, const int* __restrict__ eidx,
        const float* __restrict__ w1, const float* __restrict__ b1,
        const float* __restrict__ P, float* __restrict__ agg) {
    __shared__ float w1s[FE][16];
    __shared__ float b1s[16];
    int tid = threadIdx.x;
    if (tid < FE * 16) w1s[tid >> 4][tid & 15] = w1[tid];
    if (tid < 16) b1s[tid] = b1[tid];
    __syncthreads();
    int eg = blockIdx.x * 8 + (tid >> 5);
    int lane = tid & 31;
    if (eg >= NE) return;
    int src = eidx[eg];
    int dst = eidx[NE + eg];
    float h = 0.f;
    if (lane < 16) {
        h = b1s[lane];
        #pragma unroll
        for (int i = 0; i < FE; ++i) h += ea[eg * FE + i] * w1s[i][lane];
        h = fmaxf(h, 0.f);
    }
    const float* Pr = P + (size_t)src * PCOLS;
    float acc = Pr[512 + lane];                 // b2 term
    #pragma unroll
    for (int k = 0; k < 16; ++k) {
        float hk = __shfl(h, k, 32);
        acc += hk * Pr[k * 32 + lane];
    }
    atomicAdd(&agg[(size_t)dst * EMB + lane], acc);
}

// x_next = relu(agg + root_term + bias)
__global__ void combine_kernel(const float* __restrict__ agg, const float* __restrict__ P,
                               const float* __restrict__ bias, float* __restrict__ xout) {
    int idx = blockIdx.x * blockDim.x + threadIdx.x;
    if (idx >= NN * EMB) return;
    int n = idx >> 5, o = idx & 31;
    float v = agg[idx] + P[(size_t)n * PCOLS + 544 + o] + bias[o];
    xout[idx] = fmaxf(v, 0.f);
}

// segment max via int-bit atomicMax (values >= 0 after relu; gbuf zero-init)
__global__ void segmax_kernel(const float* __restrict__ h, const int* __restrict__ batch,
                              float* __restrict__ gbuf, int col_off) {
    int idx = blockIdx.x * blockDim.x + threadIdx.x;
    if (idx >= NN * EMB) return;
    int n = idx >> 5, o = idx & 31;
    int g = batch[n];
    atomicMax((int*)&gbuf[(size_t)g * 64 + col_off + o], __float_as_int(h[idx]));
}

// out[g] = (x@lin0_w + lin0_b) @ lin1_w + lin1_b, one 64-thread block per graph
__global__ __launch_bounds__(64) void final_mlp_kernel(
        const float* __restrict__ gbuf,
        const float* __restrict__ w0, const float* __restrict__ b0,
        const float* __restrict__ w1v, const float* __restrict__ b1v,
        float* __restrict__ out) {
    int g = blockIdx.x;
    int j = threadIdx.x;
    const float* xr = gbuf + (size_t)g * 64;
    float y = b0[j];
    for (int i = 0; i < 64; ++i) y += xr[i] * w0[i * 64 + j];
    float t = y * w1v[j];
    #pragma unroll
    for (int off = 32; off > 0; off >>= 1) t += __shfl_down(t, off, 64);
    if (j == 0) out[g] = t + b1v[0];
}

extern "C" void kernel_launch(void* const* d_in, const int* in_sizes, int n_in,
                              void* d_out, int out_size, void* d_ws, size_t ws_size,
                              hipStream_t stream) {
    (void)in_sizes; (void)n_in; (void)out_size; (void)ws_size;
    float* ws = (float*)d_ws;
    size_t off = 0;
    float* P    = ws + off; off += (size_t)NN * PCOLS;  // 14.4M floats
    float* xa   = ws + off; off += (size_t)NN * EMB;
    float* xb   = ws + off; off += (size_t)NN * EMB;
    float* agg  = ws + off; off += (size_t)NN * EMB;
    float* gbuf = ws + off; off += (size_t)NG * 64;

    hipMemsetAsync(gbuf, 0, (size_t)NG * 64 * sizeof(float), stream);

    for (int br = 0; br < 2; ++br) {
        const float* xin  = (const float*)d_in[br];        // x_p / x_d
        const float* ea   = (const float*)d_in[2 + br];    // edge_attr
        const int*   eidx = (const int*)d_in[4 + br];      // edge_index [2,E]
        const int*   batch= (const int*)d_in[6 + br];      // batch
        int wb = 8 + br * 12;

        const float* cur = xin;
        float* nxt = xa;
        for (int l = 0; l < 2; ++l) {
            const float* w1   = (const float*)d_in[wb + l * 6 + 0];
            const float* b1   = (const float*)d_in[wb + l * 6 + 1];
            const float* w2   = (const float*)d_in[wb + l * 6 + 2];
            const float* b2v  = (const float*)d_in[wb + l * 6 + 3];
            const float* root = (const float*)d_in[wb + l * 6 + 4];
            const float* bias = (const float*)d_in[wb + l * 6 + 5];

            pgemm_kernel<<<(NN + 15) / 16, 256, 0, stream>>>(cur, w2, b2v, root, P);
            hipMemsetAsync(agg, 0, (size_t)NN * EMB * sizeof(float), stream);
            edge_msg_kernel<<<(NE + 7) / 8, 256, 0, stream>>>(ea, eidx, w1, b1, P, agg);
            combine_kernel<<<(NN * EMB + 255) / 256, 256, 0, stream>>>(agg, P, bias, nxt);
            cur = nxt;
            nxt = (nxt == xa) ? xb : xa;
        }
        segmax_kernel<<<(NN * EMB + 255) / 256, 256, 0, stream>>>(cur, batch, gbuf, br * 32);
    }

    final_mlp_kernel<<<NG, 64, 0, stream>>>(gbuf,
        (const float*)d_in[32], (const float*)d_in[33],
        (const float*)d_in[34], (const float*)d_in[35],
        (float*)d_out);
}

// Round 3
// 275.233 us; speedup vs baseline: 1.1236x; 1.1236x over previous
//
#include <hip/hip_runtime.h>

#define NN 25000
#define NE 100000
#define NG 512
#define PC 576        // P columns: 512 (w2) + 32 (b2) + 32 (root)
#define NPAD 25024    // padded node rows in workspace

typedef __attribute__((ext_vector_type(8))) short short8;
typedef __attribute__((ext_vector_type(4))) float f32x4;

__device__ __forceinline__ float bf2f(unsigned short u) {
    union { unsigned u; float f; } v; v.u = ((unsigned)u) << 16; return v.f;
}
__device__ __forceinline__ unsigned short f2bf(float f) {
    union { float f; unsigned u; } v; v.f = f;
    return (unsigned short)((v.u + 0x7FFFu + ((v.u >> 16) & 1u)) >> 16);
}

struct PrepArgs {
    const float* w2[4];
    const float* b2[4];
    const float* root[4];
};

// Wt[L][c][i] (bf16, B^T layout: 8 consecutive k per 16B) from fp32 weights.
//   c<512: w2[L][(c>>5)*1024 + i*32 + (c&31)]; c<544: b2[L][i*32+(c-512)];
//   else:  root[L][i*32+(c-544)]
__global__ __launch_bounds__(256) void prep_kernel(PrepArgs pa, unsigned short* __restrict__ Wt) {
    int idx = blockIdx.x * 256 + threadIdx.x;
    if (idx >= 4 * PC * 32) return;
    int L = idx / (PC * 32);
    int r = idx % (PC * 32);
    int c = r >> 5, i = r & 31;
    float v;
    if (c < 512)      v = pa.w2[L][(c >> 5) * 1024 + i * 32 + (c & 31)];
    else if (c < 544) v = pa.b2[L][i * 32 + (c - 512)];
    else              v = pa.root[L][i * 32 + (c - 544)];
    Wt[idx] = f2bf(v);
}

// P[n,c] = sum_i xin[n,i] * Wt[c][i] via mfma_f32_16x16x32_bf16.
// 4 waves/block, 16 nodes/wave, 64 nodes/block. Also zeroes agg rows of this block.
// FIRST: xin = x0 fp32.  !FIRST: x = relu(agg + Pprev_root + bias) built in-register
// (fused combine of previous layer); agg rows re-zeroed after being read.
template<bool FIRST>
__global__ __launch_bounds__(256) void pgemm_kernel(
        const float* __restrict__ x0,
        const unsigned short* __restrict__ Pprev,
        const float* __restrict__ bias_prev,
        const unsigned short* __restrict__ Wt,     // layer offset pre-applied
        unsigned short* __restrict__ P,
        float* __restrict__ agg) {
    int tid = threadIdx.x;
    int wv = tid >> 6, l = tid & 63;
    int nblk = blockIdx.x * 64;
    int n0 = nblk + wv * 16;
    int lr = l & 15, kg = l >> 4;             // A-row / B-col / D-col = lr; k-group = kg
    int n = n0 + lr;
    int nc = n < NN ? n : NN - 1;             // clamp OOB reads (stores are guarded)

    short8 afrag;
    if (FIRST) {
        const float4* xp = (const float4*)(x0 + (size_t)nc * 32 + kg * 8);
        float4 v0 = xp[0], v1 = xp[1];
        afrag[0] = (short)f2bf(v0.x); afrag[1] = (short)f2bf(v0.y);
        afrag[2] = (short)f2bf(v0.z); afrag[3] = (short)f2bf(v0.w);
        afrag[4] = (short)f2bf(v1.x); afrag[5] = (short)f2bf(v1.y);
        afrag[6] = (short)f2bf(v1.z); afrag[7] = (short)f2bf(v1.w);
    } else {
        const float4* ap = (const float4*)(agg + (size_t)nc * 32 + kg * 8);
        float4 a0 = ap[0], a1 = ap[1];
        short8 rt = *(const short8*)(Pprev + (size_t)nc * PC + 544 + kg * 8);
        const float4* bp = (const float4*)(bias_prev + kg * 8);
        float4 b0 = bp[0], b1 = bp[1];
        float t;
        t = a0.x + bf2f((unsigned short)rt[0]) + b0.x; afrag[0] = (short)f2bf(fmaxf(t, 0.f));
        t = a0.y + bf2f((unsigned short)rt[1]) + b0.y; afrag[1] = (short)f2bf(fmaxf(t, 0.f));
        t = a0.z + bf2f((unsigned short)rt[2]) + b0.z; afrag[2] = (short)f2bf(fmaxf(t, 0.f));
        t = a0.w + bf2f((unsigned short)rt[3]) + b0.w; afrag[3] = (short)f2bf(fmaxf(t, 0.f));
        t = a1.x + bf2f((unsigned short)rt[4]) + b1.x; afrag[4] = (short)f2bf(fmaxf(t, 0.f));
        t = a1.y + bf2f((unsigned short)rt[5]) + b1.y; afrag[5] = (short)f2bf(fmaxf(t, 0.f));
        t = a1.z + bf2f((unsigned short)rt[6]) + b1.z; afrag[6] = (short)f2bf(fmaxf(t, 0.f));
        t = a1.w + bf2f((unsigned short)rt[7]) + b1.w; afrag[7] = (short)f2bf(fmaxf(t, 0.f));
    }
    if (!FIRST) __syncthreads();              // all agg reads done before re-zeroing

    // zero agg rows nblk..nblk+63 (2048 floats = 512 float4)
    float4 zf = make_float4(0.f, 0.f, 0.f, 0.f);
    float4* az = (float4*)(agg + (size_t)nblk * 32);
    az[tid] = zf; az[tid + 256] = zf;

    f32x4 z4 = {0.f, 0.f, 0.f, 0.f};
    for (int ct = 0; ct < 36; ++ct) {
        short8 bfrag = *(const short8*)(Wt + ct * 512 + lr * 32 + kg * 8);
        f32x4 d = __builtin_amdgcn_mfma_f32_16x16x32_bf16(afrag, bfrag, z4, 0, 0, 0);
        int col = ct * 16 + lr;
        #pragma unroll
        for (int j = 0; j < 4; ++j) {
            int node = n0 + kg * 4 + j;       // D: col=lane&15, row=(lane>>4)*4+j
            if (node < NN) P[(size_t)node * PC + col] = f2bf(d[j]);
        }
    }
}

// per edge: h = relu(ea@w1+b1); acc[o] = P[src,512+o] + sum_{k: h_k!=0} h_k*P[src,k*32+o];
// atomicAdd into agg[dst]. 32 lanes/edge, 8 edges per 256-thread block.
__global__ __launch_bounds__(256) void edge_msg_kernel(
        const float* __restrict__ ea, const int* __restrict__ eidx,
        const float* __restrict__ w1, const float* __restrict__ b1,
        const unsigned short* __restrict__ P, float* __restrict__ agg) {
    __shared__ float w1s[8][16];
    __shared__ float b1s[16];
    int tid = threadIdx.x;
    if (tid < 128) w1s[tid >> 4][tid & 15] = w1[tid];
    if (tid < 16) b1s[tid] = b1[tid];
    __syncthreads();
    int eg = blockIdx.x * 8 + (tid >> 5);
    int lane = tid & 31;
    if (eg >= NE) return;
    int src = eidx[eg], dst = eidx[NE + eg];
    float h = 0.f;
    if (lane < 16) {
        h = b1s[lane];
        #pragma unroll
        for (int i = 0; i < 8; ++i) h += ea[eg * 8 + i] * w1s[i][lane];
        h = fmaxf(h, 0.f);
    }
    const unsigned short* Pr = P + (size_t)src * PC;
    float acc = bf2f(Pr[512 + lane]);                 // b2 term
    #pragma unroll
    for (int k = 0; k < 16; ++k) {
        float hk = __shfl(h, k, 32);
        if (hk != 0.f) acc += hk * bf2f(Pr[k * 32 + lane]);
    }
    atomicAdd(&agg[(size_t)dst * 32 + lane], acc);
}

// last-layer combine fused with global_max_pool (int-bit atomicMax, values >= 0)
__global__ __launch_bounds__(256) void combine_segmax_kernel(
        const float* __restrict__ agg, const unsigned short* __restrict__ P,
        const float* __restrict__ bias, const int* __restrict__ batch,
        float* __restrict__ gbuf, int coloff) {
    int idx = blockIdx.x * 256 + threadIdx.x;
    if (idx >= NN * 32) return;
    int n = idx >> 5, o = idx & 31;
    float v = agg[idx] + bf2f(P[(size_t)n * PC + 544 + o]) + bias[o];
    v = fmaxf(v, 0.f);
    atomicMax((int*)&gbuf[(size_t)batch[n] * 64 + coloff + o], __float_as_int(v));
}

// out[g] = (x@lin0_w + lin0_b) @ lin1_w + lin1_b, one 64-thread block per graph
__global__ __launch_bounds__(64) void final_mlp_kernel(
        const float* __restrict__ gbuf,
        const float* __restrict__ w0, const float* __restrict__ b0,
        const float* __restrict__ w1v, const float* __restrict__ b1v,
        float* __restrict__ out) {
    int g = blockIdx.x;
    int j = threadIdx.x;
    const float* xr = gbuf + (size_t)g * 64;
    float y = b0[j];
    for (int i = 0; i < 64; ++i) y += xr[i] * w0[i * 64 + j];
    float t = y * w1v[j];
    #pragma unroll
    for (int off = 32; off > 0; off >>= 1) t += __shfl_down(t, off, 64);
    if (j == 0) out[g] = t + b1v[0];
}

extern "C" void kernel_launch(void* const* d_in, const int* in_sizes, int n_in,
                              void* d_out, int out_size, void* d_ws, size_t ws_size,
                              hipStream_t stream) {
    (void)in_sizes; (void)n_in; (void)out_size; (void)ws_size;
    char* w = (char*)d_ws;
    unsigned short* Wt  = (unsigned short*)w;                 w += 4 * PC * 32 * 2;      // 147 KB
    unsigned short* Pa  = (unsigned short*)w;                 w += (size_t)NPAD * PC * 2; // 28.8 MB
    unsigned short* Pb  = (unsigned short*)w;                 w += (size_t)NPAD * PC * 2; // 28.8 MB
    float*          agg = (float*)w;                          w += (size_t)NPAD * 32 * 4; // 3.2 MB
    float*          gbuf= (float*)w;                          w += (size_t)NG * 64 * 4;   // 128 KB

    hipMemsetAsync(gbuf, 0, (size_t)NG * 64 * sizeof(float), stream);

    PrepArgs pa;
    for (int L = 0; L < 4; ++L) {
        int base = 8 + (L >> 1) * 12 + (L & 1) * 6;
        pa.w2[L]   = (const float*)d_in[base + 2];
        pa.b2[L]   = (const float*)d_in[base + 3];
        pa.root[L] = (const float*)d_in[base + 4];
    }
    prep_kernel<<<(4 * PC * 32 + 255) / 256, 256, 0, stream>>>(pa, Wt);

    for (int br = 0; br < 2; ++br) {
        const float* xin  = (const float*)d_in[br];
        const float* ea   = (const float*)d_in[2 + br];
        const int*   eidx = (const int*)d_in[4 + br];
        const int*   batch= (const int*)d_in[6 + br];
        int base = 8 + br * 12;
        const float* w1_0  = (const float*)d_in[base + 0];
        const float* b1_0  = (const float*)d_in[base + 1];
        const float* bias0 = (const float*)d_in[base + 5];
        const float* w1_1  = (const float*)d_in[base + 6];
        const float* b1_1  = (const float*)d_in[base + 7];
        const float* bias1 = (const float*)d_in[base + 11];
        const unsigned short* Wt0 = Wt + (size_t)(br * 2)     * PC * 32;
        const unsigned short* Wt1 = Wt + (size_t)(br * 2 + 1) * PC * 32;

        pgemm_kernel<true><<<(NN + 63) / 64, 256, 0, stream>>>(
            xin, Pa, bias0, Wt0, Pa, agg);
        edge_msg_kernel<<<(NE + 7) / 8, 256, 0, stream>>>(ea, eidx, w1_0, b1_0, Pa, agg);
        pgemm_kernel<false><<<(NN + 63) / 64, 256, 0, stream>>>(
            xin, Pa, bias0, Wt1, Pb, agg);
        edge_msg_kernel<<<(NE + 7) / 8, 256, 0, stream>>>(ea, eidx, w1_1, b1_1, Pb, agg);
        combine_segmax_kernel<<<(NN * 32 + 255) / 256, 256, 0, stream>>>(
            agg, Pb, bias1, batch, gbuf, br * 32);
    }

    final_mlp_kernel<<<NG, 64, 0, stream>>>(gbuf,
        (const float*)d_in[32], (const float*)d_in[33],
        (const float*)d_in[34], (const float*)d_in[35],
        (float*)d_out);
}